// Round 1
// baseline (677.564 us; speedup 1.0000x reference)
//
#include <hip/hip_runtime.h>
#include <math.h>

#define BN 4096
#define DN 256

// ---- workspace layout ----
// float offsets
#define CE_F     0                      // [4096][256] gathered class embeddings
#define X2_F     1048576                // [4096]
#define XN_F     1052672
#define PSI_F    1056768
#define LOGC_F   1060864
#define Y2I_F    1064960
#define Y2T_F    1069056
// byte offsets
#define HIST_B   4292608                // int[1024]
#define ACC_B    4296704                // double[2] : {entl_sum, hyp_row_sum}
#define PART_F   1074180                // float4[2 pair][2 jhalf][4096] online-softmax partials

#define CLIPV 0.99999f
#define LOG_EPS_C (-11.512925464970229f)   // ln(1e-5)

__global__ void hist_kernel(const int* __restrict__ labels, int* __restrict__ hist) {
    int i = blockIdx.x * 256 + threadIdx.x;
    if (i < BN) atomicAdd(&hist[labels[i]], 1);
}

__global__ void prep_x_kernel(const float* __restrict__ cw, const int* __restrict__ labels,
                              const int* __restrict__ hist, float* __restrict__ ws) {
    int row = blockIdx.x;
    int lab = labels[row];
    int t = threadIdx.x;                                   // 64 threads
    float4 v = ((const float4*)(cw + (size_t)lab * DN))[t];
    ((float4*)(ws + CE_F + (size_t)row * DN))[t] = v;
    float sq = v.x*v.x + v.y*v.y + v.z*v.z + v.w*v.w;
    #pragma unroll
    for (int off = 32; off > 0; off >>= 1) sq += __shfl_down(sq, off);
    if (t == 0) {
        ws[X2_F + row] = sq;
        float xn = sqrtf(sq);
        ws[XN_F + row] = xn;
        float a = 0.1f * (1.f - sq) / xn;
        a = fminf(fmaxf(a, -CLIPV), CLIPV);
        ws[PSI_F + row] = asinf(a);
        ws[LOGC_F + row] = logf(1.0f / (float)hist[lab] + 1e-5f);
    }
}

__global__ void prep_y_kernel(const float* __restrict__ yimg, const float* __restrict__ ytxt,
                              float* __restrict__ ws) {
    int row = blockIdx.x;
    const float* Y = blockIdx.y ? ytxt : yimg;
    float* o = ws + (blockIdx.y ? Y2T_F : Y2I_F);
    int t = threadIdx.x;
    float4 v = ((const float4*)(Y + (size_t)row * DN))[t];
    float sq = v.x*v.x + v.y*v.y + v.z*v.z + v.w*v.w;
    #pragma unroll
    for (int off = 32; off > 0; off >>= 1) sq += __shfl_down(sq, off);
    if (t == 0) o[row] = sq;
}

// 64x64 tile per block, K=256 fully LDS-resident, 4x4 per thread, fp32 FMA.
// grid = (64 row tiles, 2 j-halves, 2 pairs) = 256 blocks.
__launch_bounds__(256, 1)
__global__ void fused_kernel(const float* __restrict__ yimg, const float* __restrict__ ytxt,
                             const int* __restrict__ labels, float* __restrict__ ws,
                             double* __restrict__ accum, float* __restrict__ part) {
    __shared__ float xs[DN * 68];   // xs[k*68 + r], r = row within tile
    __shared__ float ys[DN * 68];   // ys[k*68 + c]
    __shared__ float y2sh[64];
    __shared__ int   labysh[64];

    const int tid = threadIdx.x;
    const int tx = tid & 15;
    const int ty = tid >> 4;
    const int i0 = blockIdx.x * 64;
    const int jhalf = blockIdx.y;
    const int pair = blockIdx.z;
    const float* Y   = pair ? ytxt : yimg;
    const float* y2g = ws + (pair ? Y2T_F : Y2I_F);
    const float* ce  = ws + CE_F;

    // ---- stage x tile (transposed; r = lane -> conflict-free-ish writes) ----
    {
        int r = tid & 63;
        int kb = tid >> 6;                    // 0..3
        #pragma unroll
        for (int it = 0; it < 16; ++it) {
            int k4 = kb + it * 4;             // 0..63
            float4 v = ((const float4*)(ce + (size_t)(i0 + r) * DN))[k4];
            xs[(k4*4 + 0) * 68 + r] = v.x;
            xs[(k4*4 + 1) * 68 + r] = v.y;
            xs[(k4*4 + 2) * 68 + r] = v.z;
            xs[(k4*4 + 3) * 68 + r] = v.w;
        }
    }

    // ---- per-row constants ----
    float x2r[4], xnr[4], psir[4], onepx2[4], bcr[4], bcsqr[4];
    int labxr[4];
    #pragma unroll
    for (int ri = 0; ri < 4; ++ri) {
        int row = i0 + ty * 4 + ri;
        float x2 = ws[X2_F + row];
        x2r[ri] = x2;
        xnr[ri] = ws[XN_F + row];
        psir[ri] = ws[PSI_F + row];
        onepx2[ri] = 1.f + x2;
        float bc = 1.f - x2;
        bcr[ri] = bc;
        bcsqr[ri] = bc * bc;
        labxr[ri] = labels[row];
    }

    float acc_entl = 0.f;
    float mr[4], sr[4], tr[4], ppr[4];
    #pragma unroll
    for (int ri = 0; ri < 4; ++ri) { mr[ri] = -1e30f; sr[ri] = 0.f; tr[ri] = 0.f; ppr[ri] = 0.f; }

    for (int jt = 0; jt < 32; ++jt) {
        const int j0 = (jhalf * 32 + jt) * 64;
        __syncthreads();   // previous tile fully consumed before overwrite (also covers x staging)
        {
            int r = tid & 63;
            int kb = tid >> 6;
            #pragma unroll
            for (int it = 0; it < 16; ++it) {
                int k4 = kb + it * 4;
                float4 v = ((const float4*)(Y + (size_t)(j0 + r) * DN))[k4];
                ys[(k4*4 + 0) * 68 + r] = v.x;
                ys[(k4*4 + 1) * 68 + r] = v.y;
                ys[(k4*4 + 2) * 68 + r] = v.z;
                ys[(k4*4 + 3) * 68 + r] = v.w;
            }
        }
        if (tid < 64) { y2sh[tid] = y2g[j0 + tid]; labysh[tid] = labels[j0 + tid]; }
        __syncthreads();

        // ---- dot tile ----
        float acc[4][4] = {{0.f}};
        #pragma unroll 8
        for (int k = 0; k < DN; ++k) {
            float4 a = *(const float4*)&xs[k * 68 + ty * 4];
            float4 b = *(const float4*)&ys[k * 68 + tx * 4];
            acc[0][0] = fmaf(a.x, b.x, acc[0][0]);
            acc[0][1] = fmaf(a.x, b.y, acc[0][1]);
            acc[0][2] = fmaf(a.x, b.z, acc[0][2]);
            acc[0][3] = fmaf(a.x, b.w, acc[0][3]);
            acc[1][0] = fmaf(a.y, b.x, acc[1][0]);
            acc[1][1] = fmaf(a.y, b.y, acc[1][1]);
            acc[1][2] = fmaf(a.y, b.z, acc[1][2]);
            acc[1][3] = fmaf(a.y, b.w, acc[1][3]);
            acc[2][0] = fmaf(a.z, b.x, acc[2][0]);
            acc[2][1] = fmaf(a.z, b.y, acc[2][1]);
            acc[2][2] = fmaf(a.z, b.z, acc[2][2]);
            acc[2][3] = fmaf(a.z, b.w, acc[2][3]);
            acc[3][0] = fmaf(a.w, b.x, acc[3][0]);
            acc[3][1] = fmaf(a.w, b.y, acc[3][1]);
            acc[3][2] = fmaf(a.w, b.z, acc[3][2]);
            acc[3][3] = fmaf(a.w, b.w, acc[3][3]);
        }

        // ---- elementwise: E (entailment) + dist + online softmax ----
        #pragma unroll
        for (int ci = 0; ci < 4; ++ci) {
            float y2 = y2sh[tx * 4 + ci];
            int lby = labysh[tx * 4 + ci];
            float onepy2 = 1.f + y2;
            #pragma unroll
            for (int ri = 0; ri < 4; ++ri) {
                float dot = acc[ri][ci];
                bool pos = (labxr[ri] == lby);
                float m2dot = -2.f * dot;
                // shared subexpression: 1 + x2*y2 - 2*dot  (E inner sqrt arg AND dist denom)
                float q2 = fmaf(x2r[ri], y2, 1.f) + m2dot;
                // --- entailment E ---
                float xyd2 = x2r[ri] + y2 + m2dot;
                float xyd = sqrtf(fmaxf(xyd2, 0.f));
                float q = sqrtf(q2);
                float den = xnr[ri] * xyd * q;
                float numer = fmaf(dot, onepx2[ri], -x2r[ri] * onepy2);
                float arg = numer / den;
                arg = fminf(fmaxf(arg, -CLIPV), CLIPV);
                float theta = acosf(arg);
                float E = fmaxf(theta - psir[ri], 0.f);
                acc_entl += pos ? E : fmaxf(1.f - E, 0.f);
                // --- hyperbolic distance ---
                float A = onepy2 + m2dot;                       // 1 + 2xy + y2, xy = -dot
                float nsq = fmaf(A, fmaf(A, x2r[ri], bcr[ri] * m2dot), bcsqr[ri] * y2);
                float norm = sqrtf(fmaxf(nsq, 0.f)) / (q2 + 1e-5f);
                float xc = fminf(norm, CLIPV);
                float dist = log1pf(xc) - log1pf(-xc);          // 2*artanh(xc)
                float nd = -dist;
                // --- online softmax state ---
                float M = fmaxf(mr[ri], nd);
                float ea = __expf(mr[ri] - M);
                float eb = __expf(nd - M);
                sr[ri] = fmaf(sr[ri], ea, eb);
                tr[ri] = fmaf(tr[ri], ea, eb * nd);
                ppr[ri] = fmaf(ppr[ri], ea, pos ? eb : 0.f);
                mr[ri] = M;
            }
        }
    }

    // ---- merge online states across the 16 column-threads (same wave, lanes differ in low 4 bits) ----
    #pragma unroll
    for (int off = 1; off < 16; off <<= 1) {
        #pragma unroll
        for (int ri = 0; ri < 4; ++ri) {
            float mo = __shfl_xor(mr[ri], off);
            float so = __shfl_xor(sr[ri], off);
            float to = __shfl_xor(tr[ri], off);
            float po = __shfl_xor(ppr[ri], off);
            float M = fmaxf(mr[ri], mo);
            float ea = __expf(mr[ri] - M);
            float eb = __expf(mo - M);
            sr[ri] = sr[ri] * ea + so * eb;
            tr[ri] = tr[ri] * ea + to * eb;
            ppr[ri] = ppr[ri] * ea + po * eb;
            mr[ri] = M;
        }
    }
    if (tx == 0) {
        #pragma unroll
        for (int ri = 0; ri < 4; ++ri) {
            int row = i0 + ty * 4 + ri;
            ((float4*)part)[((size_t)(pair * 2 + jhalf)) * BN + row] =
                make_float4(mr[ri], sr[ri], tr[ri], ppr[ri]);
        }
    }

    // ---- entailment sum: wave reduce then one double atomic per wave ----
    #pragma unroll
    for (int off = 32; off > 0; off >>= 1) acc_entl += __shfl_down(acc_entl, off);
    if ((tid & 63) == 0) atomicAdd(&accum[0], (double)acc_entl);
}

__global__ void merge_kernel(const float* __restrict__ part, const float* __restrict__ logcg,
                             double* __restrict__ accum) {
    __shared__ double sbuf[4];
    int idx = blockIdx.x * 256 + threadIdx.x;     // 0..8191
    int pair = idx >> 12;
    int row = idx & 4095;
    float4 s0 = ((const float4*)part)[((size_t)(pair * 2 + 0)) * BN + row];
    float4 s1 = ((const float4*)part)[((size_t)(pair * 2 + 1)) * BN + row];
    float M = fmaxf(s0.x, s1.x);
    float e0 = __expf(s0.x - M);
    float e1 = __expf(s1.x - M);
    float S  = s0.y * e0 + s1.y * e1;
    float T  = s0.z * e0 + s1.z * e1;
    float PP = s0.w * e0 + s1.w * e1;
    float invS = 1.f / S;
    float fp = PP * invS;
    // row loss = sum_j p*logp - sum_pos p*ln(1/cnt+eps) - sum_neg p*ln(eps)
    float rl = T * invS - M - logf(S) - fp * logcg[row] - (1.f - fp) * LOG_EPS_C;
    double v = (double)rl;
    #pragma unroll
    for (int off = 32; off > 0; off >>= 1) v += __shfl_down(v, off);
    int lane = threadIdx.x & 63, w = threadIdx.x >> 6;
    if (lane == 0) sbuf[w] = v;
    __syncthreads();
    if (threadIdx.x == 0) {
        double tot = sbuf[0] + sbuf[1] + sbuf[2] + sbuf[3];
        atomicAdd(&accum[1], tot);
    }
}

__global__ void finalize_kernel(const double* __restrict__ accum, float* __restrict__ out) {
    if (threadIdx.x == 0) {
        float e = (float)accum[0];
        float h = (float)(accum[1] * (1.0 / 4096.0));
        out[0] = e;
        out[1] = h;
        out[2] = e + h;
    }
}

extern "C" void kernel_launch(void* const* d_in, const int* in_sizes, int n_in,
                              void* d_out, int out_size, void* d_ws, size_t ws_size,
                              hipStream_t stream) {
    (void)in_sizes; (void)n_in; (void)out_size; (void)ws_size;
    const float* img = (const float*)d_in[0];
    const float* txt = (const float*)d_in[1];
    const float* cw  = (const float*)d_in[2];
    const int* labels = (const int*)d_in[3];
    float* out = (float*)d_out;
    char* wsb = (char*)d_ws;
    float* wsf = (float*)d_ws;
    int* hist = (int*)(wsb + HIST_B);
    double* accum = (double*)(wsb + ACC_B);
    float* part = wsf + PART_F;

    hipMemsetAsync(wsb + HIST_B, 0, 4096 + 16, stream);
    hist_kernel<<<16, 256, 0, stream>>>(labels, hist);
    prep_x_kernel<<<BN, 64, 0, stream>>>(cw, labels, hist, wsf);
    prep_y_kernel<<<dim3(BN, 2), 64, 0, stream>>>(img, txt, wsf);
    fused_kernel<<<dim3(64, 2, 2), 256, 0, stream>>>(img, txt, labels, wsf, accum, part);
    merge_kernel<<<32, 256, 0, stream>>>(part, wsf + LOGC_F, accum);
    finalize_kernel<<<1, 64, 0, stream>>>(accum, out);
}

// Round 2
// 197.853 us; speedup vs baseline: 3.4246x; 3.4246x over previous
//
#include <hip/hip_runtime.h>
#include <math.h>

#define BB 4096
#define DD 256

typedef __attribute__((ext_vector_type(4))) float f32x4;
typedef __bf16 bf16x8 __attribute__((ext_vector_type(8)));

// ---- workspace byte offsets ----
#define AHI_B   (size_t)(0)                    // [4096][256] bf16 (2 MB)
#define ALO_B   (size_t)(AHI_B + 2097152)
#define YHI_B   (size_t)(ALO_B + 2097152)      // [2][4096][256] bf16 (4 MB)
#define YLO_B   (size_t)(YHI_B + 4194304)
#define RS0_B   (size_t)(YLO_B + 4194304)      // [4096] float4: x2, xn, psi, labx
#define RS1_B   (size_t)(RS0_B + 65536)        // [4096] float4: 1+x2, 1-x2, (1-x2)^2, logc
#define YS_B    (size_t)(RS1_B + 65536)        // [2][4096] float2: y2, laby
#define PART_B  (size_t)(YS_B + 65536)         // [2][32][4096] float4 (4 MB): S,T,PP
#define HIST_B  (size_t)(PART_B + 4194304)     // int[1024]
#define ACC_B   (size_t)(HIST_B + 4096)        // double[2]

#define CLIPV 0.99999f
#define LOG_EPS_C (-11.512925464970229f)   // ln(1e-5)
#define LN2F 0.6931471805599453f

__device__ __forceinline__ void gload16(const void* g, void* l) {
    __builtin_amdgcn_global_load_lds((const __attribute__((address_space(1))) void*)g,
                                     (__attribute__((address_space(3))) void*)l, 16, 0, 0);
}

__device__ __forceinline__ unsigned short f2bf(float f) {
    unsigned u = __float_as_uint(f);
    u += 0x7fffu + ((u >> 16) & 1u);
    return (unsigned short)(u >> 16);
}

__global__ void hist_kernel(const int* __restrict__ labels, int* __restrict__ hist) {
    int i = blockIdx.x * 256 + threadIdx.x;
    if (i < BB) atomicAdd(&hist[labels[i]], 1);
}

// gather class embedding row, emit bf16 hi/lo + row stats
__global__ void prep_x_kernel(const float* __restrict__ cw, const int* __restrict__ labels,
                              const int* __restrict__ hist, char* __restrict__ ws) {
    int row = blockIdx.x;
    int lab = labels[row];
    int t = threadIdx.x;                                   // 64 threads, 4 elems each
    float4 v = ((const float4*)(cw + (size_t)lab * DD))[t];
    ushort4 h, lo;
    h.x = f2bf(v.x); h.y = f2bf(v.y); h.z = f2bf(v.z); h.w = f2bf(v.w);
    lo.x = f2bf(v.x - __uint_as_float((unsigned)h.x << 16));
    lo.y = f2bf(v.y - __uint_as_float((unsigned)h.y << 16));
    lo.z = f2bf(v.z - __uint_as_float((unsigned)h.z << 16));
    lo.w = f2bf(v.w - __uint_as_float((unsigned)h.w << 16));
    ((ushort4*)(ws + AHI_B + (size_t)row * 512))[t] = h;
    ((ushort4*)(ws + ALO_B + (size_t)row * 512))[t] = lo;
    float sq = v.x*v.x + v.y*v.y + v.z*v.z + v.w*v.w;
    #pragma unroll
    for (int off = 32; off > 0; off >>= 1) sq += __shfl_down(sq, off);
    if (t == 0) {
        float xn = sqrtf(sq);
        float a = 0.1f * (1.f - sq) / xn;
        a = fminf(fmaxf(a, -CLIPV), CLIPV);
        float psi = asinf(a);
        float logc = logf(1.0f / (float)hist[lab] + 1e-5f);
        float bc = 1.f - sq;
        ((float4*)(ws + RS0_B))[row] = make_float4(sq, xn, psi, __int_as_float(lab));
        ((float4*)(ws + RS1_B))[row] = make_float4(1.f + sq, bc, bc * bc, logc);
    }
}

__global__ void prep_y_kernel(const float* __restrict__ yimg, const float* __restrict__ ytxt,
                              const int* __restrict__ labels, char* __restrict__ ws) {
    int row = blockIdx.x;
    int pair = blockIdx.y;
    const float* Y = pair ? ytxt : yimg;
    int t = threadIdx.x;
    float4 v = ((const float4*)(Y + (size_t)row * DD))[t];
    ushort4 h, lo;
    h.x = f2bf(v.x); h.y = f2bf(v.y); h.z = f2bf(v.z); h.w = f2bf(v.w);
    lo.x = f2bf(v.x - __uint_as_float((unsigned)h.x << 16));
    lo.y = f2bf(v.y - __uint_as_float((unsigned)h.y << 16));
    lo.z = f2bf(v.z - __uint_as_float((unsigned)h.z << 16));
    lo.w = f2bf(v.w - __uint_as_float((unsigned)h.w << 16));
    ((ushort4*)(ws + YHI_B + (size_t)pair * 2097152 + (size_t)row * 512))[t] = h;
    ((ushort4*)(ws + YLO_B + (size_t)pair * 2097152 + (size_t)row * 512))[t] = lo;
    float sq = v.x*v.x + v.y*v.y + v.z*v.z + v.w*v.w;
    #pragma unroll
    for (int off = 32; off > 0; off >>= 1) sq += __shfl_down(sq, off);
    if (t == 0)
        ((float2*)(ws + YS_B))[(size_t)pair * BB + row] = make_float2(sq, __int_as_float(labels[row]));
}

// 128x128 tile, split-bf16 MFMA GEMM + fused elementwise. grid (32 col, 32 row, 2 pair).
__launch_bounds__(256, 2)
__global__ void fused_kernel(char* __restrict__ ws, double* __restrict__ accum) {
    __shared__ unsigned short Ah[128 * 64], Al[128 * 64], Bh[128 * 64], Bl[128 * 64];
    __shared__ float4 rs0l[128], rs1l[128];
    __shared__ float2 ysl[128];
    __shared__ float smrg[128][8];

    const int tid = threadIdx.x;
    const int l = tid & 63;
    const int w = tid >> 6;
    const int wm = w >> 1, wn = w & 1;
    const int bx = blockIdx.x, by = blockIdx.y, pair = blockIdx.z;
    const int rowbase = by * 128, colbase = bx * 128;

    const unsigned short* Ahg = (const unsigned short*)(ws + AHI_B);
    const unsigned short* Alg = (const unsigned short*)(ws + ALO_B);
    const unsigned short* Bhg = (const unsigned short*)(ws + YHI_B) + (size_t)pair * BB * DD;
    const unsigned short* Blg = (const unsigned short*)(ws + YLO_B) + (size_t)pair * BB * DD;

    if (tid < 128) {
        rs0l[tid] = ((const float4*)(ws + RS0_B))[rowbase + tid];
        rs1l[tid] = ((const float4*)(ws + RS1_B))[rowbase + tid];
    } else {
        int c = tid - 128;
        ysl[c] = ((const float2*)(ws + YS_B))[(size_t)pair * BB + colbase + c];
    }

    f32x4 acc[4][4];
    #pragma unroll
    for (int i = 0; i < 4; ++i)
        #pragma unroll
        for (int j = 0; j < 4; ++j) acc[i][j] = (f32x4){0.f, 0.f, 0.f, 0.f};

    const int srow8 = l >> 3;             // 0..7 within 8-row segment
    const int slot  = (l & 7) ^ srow8;    // swizzled 16B slot within 128B row

    for (int c = 0; c < 4; ++c) {
        __syncthreads();
        #pragma unroll
        for (int p = 0; p < 4; ++p) {
            int s = p * 4 + w;                        // segment 0..15
            int r = s * 8 + srow8;                    // local row 0..127
            size_t eoffA = (size_t)(rowbase + r) * DD + c * 64 + slot * 8;
            size_t eoffB = (size_t)(colbase + r) * DD + c * 64 + slot * 8;
            unsigned lb = (unsigned)s * 1024;         // wave-uniform LDS base (bytes)
            gload16(Ahg + eoffA, (char*)Ah + lb);
            gload16(Alg + eoffA, (char*)Al + lb);
            gload16(Bhg + eoffB, (char*)Bh + lb);
            gload16(Blg + eoffB, (char*)Bl + lb);
        }
        asm volatile("s_waitcnt vmcnt(0)" ::: "memory");
        __syncthreads();

        #pragma unroll
        for (int ks = 0; ks < 2; ++ks) {
            const int kb = ks * 64 + 16 * (l >> 4);   // logical byte-in-row
            bf16x8 ah[4], al4[4], bh[4], bl4[4];
            #pragma unroll
            for (int mi = 0; mi < 4; ++mi) {
                int rr_ = wm * 64 + mi * 16 + (l & 15);
                int b = kb ^ ((rr_ & 7) << 4);
                ah[mi]  = *(const bf16x8*)((const char*)Ah + rr_ * 128 + b);
                al4[mi] = *(const bf16x8*)((const char*)Al + rr_ * 128 + b);
            }
            #pragma unroll
            for (int ni = 0; ni < 4; ++ni) {
                int cc_ = wn * 64 + ni * 16 + (l & 15);
                int b = kb ^ ((cc_ & 7) << 4);
                bh[ni]  = *(const bf16x8*)((const char*)Bh + cc_ * 128 + b);
                bl4[ni] = *(const bf16x8*)((const char*)Bl + cc_ * 128 + b);
            }
            #pragma unroll
            for (int mi = 0; mi < 4; ++mi)
                #pragma unroll
                for (int ni = 0; ni < 4; ++ni) {
                    acc[mi][ni] = __builtin_amdgcn_mfma_f32_16x16x32_bf16(ah[mi],  bh[ni],  acc[mi][ni], 0, 0, 0);
                    acc[mi][ni] = __builtin_amdgcn_mfma_f32_16x16x32_bf16(ah[mi],  bl4[ni], acc[mi][ni], 0, 0, 0);
                    acc[mi][ni] = __builtin_amdgcn_mfma_f32_16x16x32_bf16(al4[mi], bh[ni],  acc[mi][ni], 0, 0, 0);
                }
        }
    }

    // ---- elementwise ----
    float entl = 0.f;
    float y2c[4], opy2c[4];
    int labyc[4];
    #pragma unroll
    for (int ni = 0; ni < 4; ++ni) {
        float2 yv = ysl[wn * 64 + ni * 16 + (l & 15)];
        y2c[ni] = yv.x; labyc[ni] = __float_as_int(yv.y); opy2c[ni] = 1.f + yv.x;
    }
    #pragma unroll
    for (int mi = 0; mi < 4; ++mi) {
        #pragma unroll
        for (int rr = 0; rr < 4; ++rr) {
            int rl_ = wm * 64 + mi * 16 + (l >> 4) * 4 + rr;
            float4 r0 = rs0l[rl_], r1 = rs1l[rl_];
            float x2 = r0.x, xn = r0.y, psi = r0.z;
            int labx = __float_as_int(r0.w);
            float opx2 = r1.x, bc = r1.y, bc2 = r1.z;
            float S = 0.f, T = 0.f, PP = 0.f;
            #pragma unroll
            for (int ni = 0; ni < 4; ++ni) {
                float dot = acc[mi][ni][rr];
                float y2 = y2c[ni], opy2 = opy2c[ni];
                bool pos = (labx == labyc[ni]);
                float m2dot = -2.f * dot;
                float q2 = fmaf(x2, y2, 1.f) + m2dot;          // shared: E denom part & dist denom
                // --- entailment E ---
                float xyd = sqrtf(fmaxf(x2 + y2 + m2dot, 0.f));
                float q = sqrtf(q2);
                float den = xn * xyd * q;
                float numer = fmaf(dot, opx2, -x2 * opy2);
                float arg = numer * __builtin_amdgcn_rcpf(den);
                arg = fminf(fmaxf(arg, -CLIPV), CLIPV);
                float theta = acosf(arg);
                float E = fmaxf(theta - psi, 0.f);
                entl += pos ? E : fmaxf(1.f - E, 0.f);
                // --- hyperbolic distance ---
                float A = opy2 + m2dot;
                float nsq = fmaf(A, fmaf(A, x2, bc * m2dot), bc2 * y2);
                float norm = sqrtf(fmaxf(nsq, 0.f)) * __builtin_amdgcn_rcpf(q2 + 1e-5f);
                float xc = fminf(norm, CLIPV);
                float u = (1.f + xc) * __builtin_amdgcn_rcpf(1.f - xc);
                float nd = -LN2F * __log2f(u);                 // nd = -dist in [-12.3, 0]
                float e = __expf(nd);                          // no max-shift needed
                S += e;
                T = fmaf(e, nd, T);
                PP += pos ? e : 0.f;
            }
            #pragma unroll
            for (int off = 1; off < 16; off <<= 1) {
                S += __shfl_xor(S, off); T += __shfl_xor(T, off); PP += __shfl_xor(PP, off);
            }
            if ((l & 15) == 0) {
                smrg[rl_][wn * 4 + 0] = S; smrg[rl_][wn * 4 + 1] = T; smrg[rl_][wn * 4 + 2] = PP;
            }
        }
    }
    __syncthreads();
    if (tid < 128) {
        float4 o;
        o.x = smrg[tid][0] + smrg[tid][4];
        o.y = smrg[tid][1] + smrg[tid][5];
        o.z = smrg[tid][2] + smrg[tid][6];
        o.w = 0.f;
        ((float4*)(ws + PART_B))[((size_t)pair * 32 + bx) * BB + rowbase + tid] = o;
    }
    #pragma unroll
    for (int off = 32; off > 0; off >>= 1) entl += __shfl_xor(entl, off);
    if (l == 0) atomicAdd(&accum[0], (double)entl);
}

__global__ void merge_kernel(const char* __restrict__ ws, double* __restrict__ accum) {
    __shared__ double sbuf[4];
    int idx = blockIdx.x * 256 + threadIdx.x;     // 0..8191
    int pair = idx >> 12, row = idx & 4095;
    const float4* part = (const float4*)(ws + PART_B) + (size_t)pair * 32 * BB + row;
    float S = 0.f, T = 0.f, PP = 0.f;
    #pragma unroll 4
    for (int cb = 0; cb < 32; ++cb) {
        float4 v = part[(size_t)cb * BB];
        S += v.x; T += v.y; PP += v.z;
    }
    float logc = ((const float4*)(ws + RS1_B))[row].w;
    float invS = 1.f / S;
    float fp = PP * invS;
    float rl = T * invS - logf(S) - fp * logc - (1.f - fp) * LOG_EPS_C;
    double v = (double)rl;
    #pragma unroll
    for (int off = 32; off > 0; off >>= 1) v += __shfl_down(v, off);
    int lane = threadIdx.x & 63, wv = threadIdx.x >> 6;
    if (lane == 0) sbuf[wv] = v;
    __syncthreads();
    if (threadIdx.x == 0) atomicAdd(&accum[1], sbuf[0] + sbuf[1] + sbuf[2] + sbuf[3]);
}

__global__ void finalize_kernel(const double* __restrict__ accum, float* __restrict__ out) {
    if (threadIdx.x == 0) {
        float e = (float)accum[0];
        float h = (float)(accum[1] * (1.0 / 4096.0));
        out[0] = e;
        out[1] = h;
        out[2] = e + h;
    }
}

extern "C" void kernel_launch(void* const* d_in, const int* in_sizes, int n_in,
                              void* d_out, int out_size, void* d_ws, size_t ws_size,
                              hipStream_t stream) {
    (void)in_sizes; (void)n_in; (void)out_size; (void)ws_size;
    const float* img = (const float*)d_in[0];
    const float* txt = (const float*)d_in[1];
    const float* cw  = (const float*)d_in[2];
    const int* labels = (const int*)d_in[3];
    float* out = (float*)d_out;
    char* wsb = (char*)d_ws;
    int* hist = (int*)(wsb + HIST_B);
    double* accum = (double*)(wsb + ACC_B);

    hipMemsetAsync(wsb + HIST_B, 0, 4096 + 16, stream);
    hist_kernel<<<16, 256, 0, stream>>>(labels, hist);
    prep_x_kernel<<<BB, 64, 0, stream>>>(cw, labels, hist, wsb);
    prep_y_kernel<<<dim3(BB, 2), 64, 0, stream>>>(img, txt, labels, wsb);
    fused_kernel<<<dim3(32, 32, 2), 256, 0, stream>>>(wsb, accum);
    merge_kernel<<<32, 256, 0, stream>>>(wsb, accum);
    finalize_kernel<<<1, 64, 0, stream>>>(accum, out);
}

// Round 3
// 155.421 us; speedup vs baseline: 4.3595x; 1.2730x over previous
//
#include <hip/hip_runtime.h>
#include <math.h>

#define BB 4096
#define DD 256

typedef __attribute__((ext_vector_type(4))) float f32x4;
typedef __bf16 bf16x8 __attribute__((ext_vector_type(8)));

// ---- workspace byte offsets ----
#define AHI_B   (size_t)(0)                    // [4096][256] bf16 (2 MB)
#define ALO_B   (size_t)(AHI_B + 2097152)
#define YHI_B   (size_t)(ALO_B + 2097152)      // [2][4096][256] bf16 (4 MB)
#define YLO_B   (size_t)(YHI_B + 4194304)
#define RS0_B   (size_t)(YLO_B + 4194304)      // [4096] float4: x2, invxn, psi, labx
#define RS1_B   (size_t)(RS0_B + 65536)        // [4096] float4: 1+x2, 1-x2, (1-x2)^2, logc
#define YS_B    (size_t)(RS1_B + 65536)        // [2][4096] float2: y2, laby
#define PART_B  (size_t)(YS_B + 65536)         // [2][32][4096] float4 (4 MB): S,T,PP
#define HIST_B  (size_t)(PART_B + 4194304)     // int[1024]
#define ACC_B   (size_t)(HIST_B + 4096)        // double[2]

#define CLIPV 0.99999f
#define LOG_EPS_C (-11.512925464970229f)   // ln(1e-5)
#define LN2F 0.6931471805599453f
#define PIF 3.14159265358979323846f
// exact fp32 eval of (1+clip)/(1-clip), clip = fp32(0.99999) = 1 - 168*2^-24
#define UCLIP 199727.765625f

__device__ __forceinline__ void gload16(const void* g, void* l) {
    __builtin_amdgcn_global_load_lds((const __attribute__((address_space(1))) void*)g,
                                     (__attribute__((address_space(3))) void*)l, 16, 0, 0);
}

__device__ __forceinline__ unsigned short f2bf(float f) {
    unsigned u = __float_as_uint(f);
    u += 0x7fffu + ((u >> 16) & 1u);
    return (unsigned short)(u >> 16);
}

__global__ void hist_kernel(const int* __restrict__ labels, int* __restrict__ hist) {
    int i = blockIdx.x * 256 + threadIdx.x;
    if (i < BB) atomicAdd(&hist[labels[i]], 1);
}

// gather class embedding rows (4 per block), emit bf16 hi/lo + row stats
__global__ void prep_x_kernel(const float* __restrict__ cw, const int* __restrict__ labels,
                              const int* __restrict__ hist, char* __restrict__ ws) {
    int row = blockIdx.x * 4 + (threadIdx.x >> 6);
    int lab = labels[row];
    int t = threadIdx.x & 63;
    float4 v = ((const float4*)(cw + (size_t)lab * DD))[t];
    ushort4 h, lo;
    h.x = f2bf(v.x); h.y = f2bf(v.y); h.z = f2bf(v.z); h.w = f2bf(v.w);
    lo.x = f2bf(v.x - __uint_as_float((unsigned)h.x << 16));
    lo.y = f2bf(v.y - __uint_as_float((unsigned)h.y << 16));
    lo.z = f2bf(v.z - __uint_as_float((unsigned)h.z << 16));
    lo.w = f2bf(v.w - __uint_as_float((unsigned)h.w << 16));
    ((ushort4*)(ws + AHI_B + (size_t)row * 512))[t] = h;
    ((ushort4*)(ws + ALO_B + (size_t)row * 512))[t] = lo;
    float sq = v.x*v.x + v.y*v.y + v.z*v.z + v.w*v.w;
    #pragma unroll
    for (int off = 32; off > 0; off >>= 1) sq += __shfl_down(sq, off);
    if (t == 0) {
        float xn = sqrtf(sq);
        float a = 0.1f * (1.f - sq) / xn;
        a = fminf(fmaxf(a, -CLIPV), CLIPV);
        float psi = asinf(a);
        float logc = logf(1.0f / (float)hist[lab] + 1e-5f);
        float bc = 1.f - sq;
        ((float4*)(ws + RS0_B))[row] = make_float4(sq, 1.0f / xn, psi, __int_as_float(lab));
        ((float4*)(ws + RS1_B))[row] = make_float4(1.f + sq, bc, bc * bc, logc);
    }
}

__global__ void prep_y_kernel(const float* __restrict__ yimg, const float* __restrict__ ytxt,
                              const int* __restrict__ labels, char* __restrict__ ws) {
    int row = blockIdx.x * 4 + (threadIdx.x >> 6);
    int pair = blockIdx.y;
    const float* Y = pair ? ytxt : yimg;
    int t = threadIdx.x & 63;
    float4 v = ((const float4*)(Y + (size_t)row * DD))[t];
    ushort4 h, lo;
    h.x = f2bf(v.x); h.y = f2bf(v.y); h.z = f2bf(v.z); h.w = f2bf(v.w);
    lo.x = f2bf(v.x - __uint_as_float((unsigned)h.x << 16));
    lo.y = f2bf(v.y - __uint_as_float((unsigned)h.y << 16));
    lo.z = f2bf(v.z - __uint_as_float((unsigned)h.z << 16));
    lo.w = f2bf(v.w - __uint_as_float((unsigned)h.w << 16));
    ((ushort4*)(ws + YHI_B + (size_t)pair * 2097152 + (size_t)row * 512))[t] = h;
    ((ushort4*)(ws + YLO_B + (size_t)pair * 2097152 + (size_t)row * 512))[t] = lo;
    float sq = v.x*v.x + v.y*v.y + v.z*v.z + v.w*v.w;
    #pragma unroll
    for (int off = 32; off > 0; off >>= 1) sq += __shfl_down(sq, off);
    if (t == 0)
        ((float2*)(ws + YS_B))[(size_t)pair * BB + row] = make_float2(sq, __int_as_float(labels[row]));
}

// 128x128 tile, 512 threads (8 waves, 4x2), split-bf16 MFMA + fused elementwise.
__launch_bounds__(512, 4)
__global__ void fused_kernel(char* __restrict__ ws, double* __restrict__ accum) {
    __shared__ unsigned short Ah[128 * 64], Al[128 * 64], Bh[128 * 64], Bl[128 * 64];
    __shared__ float4 rs0l[128], rs1l[128];
    __shared__ float2 ysl[128];
    __shared__ float smrg[128][8];
    __shared__ float sAtom[8];

    const int tid = threadIdx.x;
    const int l = tid & 63;
    const int w = tid >> 6;                 // 0..7
    const int wm = w >> 1, wn = w & 1;      // 4 x 2 wave grid; 32x64 per wave
    const int bx = blockIdx.x, by = blockIdx.y, pair = blockIdx.z;
    const int rowbase = by * 128, colbase = bx * 128;

    const unsigned short* Ahg = (const unsigned short*)(ws + AHI_B);
    const unsigned short* Alg = (const unsigned short*)(ws + ALO_B);
    const unsigned short* Bhg = (const unsigned short*)(ws + YHI_B) + (size_t)pair * BB * DD;
    const unsigned short* Blg = (const unsigned short*)(ws + YLO_B) + (size_t)pair * BB * DD;

    if (tid < 128) {
        rs0l[tid] = ((const float4*)(ws + RS0_B))[rowbase + tid];
        rs1l[tid] = ((const float4*)(ws + RS1_B))[rowbase + tid];
    } else if (tid < 256) {
        int c = tid - 128;
        ysl[c] = ((const float2*)(ws + YS_B))[(size_t)pair * BB + colbase + c];
    }

    f32x4 acc[2][4];
    #pragma unroll
    for (int i = 0; i < 2; ++i)
        #pragma unroll
        for (int j = 0; j < 4; ++j) acc[i][j] = (f32x4){0.f, 0.f, 0.f, 0.f};

    const int srow8 = l >> 3;             // row within 8-row segment
    const int slot  = (l & 7) ^ srow8;    // pre-swizzled 16B source slot

    for (int c = 0; c < 4; ++c) {
        __syncthreads();
        #pragma unroll
        for (int p = 0; p < 2; ++p) {
            int s = p * 8 + w;                        // segment 0..15 (8 rows each)
            int r = s * 8 + srow8;                    // local row 0..127
            size_t eoffA = (size_t)(rowbase + r) * DD + c * 64 + slot * 8;
            size_t eoffB = (size_t)(colbase + r) * DD + c * 64 + slot * 8;
            unsigned lb = (unsigned)s * 1024;         // wave-uniform LDS base (bytes)
            gload16(Ahg + eoffA, (char*)Ah + lb);
            gload16(Alg + eoffA, (char*)Al + lb);
            gload16(Bhg + eoffB, (char*)Bh + lb);
            gload16(Blg + eoffB, (char*)Bl + lb);
        }
        asm volatile("s_waitcnt vmcnt(0)" ::: "memory");
        __syncthreads();

        #pragma unroll
        for (int ks = 0; ks < 2; ++ks) {
            const int kb = ks * 64 + 16 * (l >> 4);   // logical 16B slot byte offset in row
            bf16x8 ah[2], al2[2], bh[4], bl4[4];
            #pragma unroll
            for (int mi = 0; mi < 2; ++mi) {
                int rr_ = wm * 32 + mi * 16 + (l & 15);
                int b = kb ^ ((rr_ & 7) << 4);
                ah[mi]  = *(const bf16x8*)((const char*)Ah + rr_ * 128 + b);
                al2[mi] = *(const bf16x8*)((const char*)Al + rr_ * 128 + b);
            }
            #pragma unroll
            for (int ni = 0; ni < 4; ++ni) {
                int cc_ = wn * 64 + ni * 16 + (l & 15);
                int b = kb ^ ((cc_ & 7) << 4);
                bh[ni]  = *(const bf16x8*)((const char*)Bh + cc_ * 128 + b);
                bl4[ni] = *(const bf16x8*)((const char*)Bl + cc_ * 128 + b);
            }
            #pragma unroll
            for (int mi = 0; mi < 2; ++mi)
                #pragma unroll
                for (int ni = 0; ni < 4; ++ni) {
                    acc[mi][ni] = __builtin_amdgcn_mfma_f32_16x16x32_bf16(ah[mi],  bh[ni],  acc[mi][ni], 0, 0, 0);
                    acc[mi][ni] = __builtin_amdgcn_mfma_f32_16x16x32_bf16(ah[mi],  bl4[ni], acc[mi][ni], 0, 0, 0);
                    acc[mi][ni] = __builtin_amdgcn_mfma_f32_16x16x32_bf16(al2[mi], bh[ni],  acc[mi][ni], 0, 0, 0);
                }
        }
    }

    // ---- elementwise ----
    float entl = 0.f;
    float y2c[4], opy2c[4];
    int labyc[4];
    #pragma unroll
    for (int ni = 0; ni < 4; ++ni) {
        float2 yv = ysl[wn * 64 + ni * 16 + (l & 15)];
        y2c[ni] = yv.x; labyc[ni] = __float_as_int(yv.y); opy2c[ni] = 1.f + yv.x;
    }
    #pragma unroll
    for (int mi = 0; mi < 2; ++mi) {
        #pragma unroll
        for (int rr = 0; rr < 4; ++rr) {
            int rl_ = wm * 32 + mi * 16 + (l >> 4) * 4 + rr;
            float4 r0 = rs0l[rl_], r1 = rs1l[rl_];
            float x2 = r0.x, invxn = r0.y, psi = r0.z;
            int labx = __float_as_int(r0.w);
            float opx2 = r1.x, bc = r1.y, bc2 = r1.z;
            float S = 0.f, T = 0.f, PP = 0.f;
            #pragma unroll
            for (int ni = 0; ni < 4; ++ni) {
                float dot = acc[mi][ni][rr];
                float y2 = y2c[ni], opy2 = opy2c[ni];
                bool pos = (labx == labyc[ni]);
                float m2dot = -2.f * dot;
                float q2 = fmaf(x2, y2, 1.f) + m2dot;          // 1 + x2*y2 - 2dot
                // --- entailment E ---
                float xyd2 = x2 + y2 + m2dot;
                float rs = __builtin_amdgcn_rsqf(fmaxf(xyd2 * q2, 1e-30f));
                float numer = fmaf(dot, opx2, -x2 * opy2);
                float arg = numer * invxn * rs;
                arg = fminf(fmaxf(arg, -CLIPV), CLIPV);
                // branch-free acos (A&S 4.4.46, |err|<=2e-8)
                float ax = fabsf(arg);
                float pl = fmaf(ax, -0.0012624911f, 0.0066700901f);
                pl = fmaf(pl, ax, -0.0170881256f);
                pl = fmaf(pl, ax, 0.0308918810f);
                pl = fmaf(pl, ax, -0.0501743046f);
                pl = fmaf(pl, ax, 0.0889789874f);
                pl = fmaf(pl, ax, -0.2145988016f);
                pl = fmaf(pl, ax, 1.5707963050f);
                float racos = sqrtf(1.f - ax) * pl;
                float theta = (arg < 0.f) ? (PIF - racos) : racos;
                float E = fmaxf(theta - psi, 0.f);
                entl += pos ? E : fmaxf(1.f - E, 0.f);
                // --- hyperbolic distance + softmax terms ---
                float A_ = opy2 + m2dot;
                float nsq = fmaf(A_, fmaf(A_, x2, bc * m2dot), bc2 * y2);
                float s_ = sqrtf(fmaxf(nsq, 0.f));
                float q2e = q2 + 1e-5f;
                float u = (q2e + s_) * __builtin_amdgcn_rcpf(q2e - s_);
                u = (s_ < CLIPV * q2e) ? u : UCLIP;            // norm clipped at 0.99999
                float lu = __builtin_amdgcn_logf(u);           // log2(u)
                float e_ = __builtin_amdgcn_exp2f(-lu);        // = exp(nd)
                float nd = -LN2F * lu;                         // -dist
                S += e_;
                T = fmaf(e_, nd, T);
                PP += pos ? e_ : 0.f;
            }
            #pragma unroll
            for (int off = 1; off < 16; off <<= 1) {
                S += __shfl_xor(S, off); T += __shfl_xor(T, off); PP += __shfl_xor(PP, off);
            }
            if ((l & 15) == 0) {
                smrg[rl_][wn * 4 + 0] = S; smrg[rl_][wn * 4 + 1] = T; smrg[rl_][wn * 4 + 2] = PP;
            }
        }
    }
    __syncthreads();
    if (tid < 128) {
        float4 o;
        o.x = smrg[tid][0] + smrg[tid][4];
        o.y = smrg[tid][1] + smrg[tid][5];
        o.z = smrg[tid][2] + smrg[tid][6];
        o.w = 0.f;
        ((float4*)(ws + PART_B))[((size_t)pair * 32 + bx) * BB + rowbase + tid] = o;
    }
    #pragma unroll
    for (int off = 32; off > 0; off >>= 1) entl += __shfl_xor(entl, off);
    if (l == 0) sAtom[w] = entl;
    __syncthreads();
    if (tid == 0) {
        float tot = 0.f;
        #pragma unroll
        for (int i = 0; i < 8; ++i) tot += sAtom[i];
        atomicAdd(&accum[0], (double)tot);
    }
}

__global__ void merge_kernel(const char* __restrict__ ws, double* __restrict__ accum) {
    __shared__ double sbuf[4];
    int idx = blockIdx.x * 256 + threadIdx.x;     // 0..8191
    int pair = idx >> 12, row = idx & 4095;
    const float4* part = (const float4*)(ws + PART_B) + (size_t)pair * 32 * BB + row;
    float S = 0.f, T = 0.f, PP = 0.f;
    #pragma unroll 4
    for (int cb = 0; cb < 32; ++cb) {
        float4 v = part[(size_t)cb * BB];
        S += v.x; T += v.y; PP += v.z;
    }
    float logc = ((const float4*)(ws + RS1_B))[row].w;
    float invS = 1.f / S;
    float fp = PP * invS;
    float rl = T * invS - logf(S) - fp * logc - (1.f - fp) * LOG_EPS_C;
    double v = (double)rl;
    #pragma unroll
    for (int off = 32; off > 0; off >>= 1) v += __shfl_down(v, off);
    int lane = threadIdx.x & 63, wv = threadIdx.x >> 6;
    if (lane == 0) sbuf[wv] = v;
    __syncthreads();
    if (threadIdx.x == 0) atomicAdd(&accum[1], sbuf[0] + sbuf[1] + sbuf[2] + sbuf[3]);
}

__global__ void finalize_kernel(const double* __restrict__ accum, float* __restrict__ out) {
    if (threadIdx.x == 0) {
        float e = (float)accum[0];
        float h = (float)(accum[1] * (1.0 / 4096.0));
        out[0] = e;
        out[1] = h;
        out[2] = e + h;
    }
}

extern "C" void kernel_launch(void* const* d_in, const int* in_sizes, int n_in,
                              void* d_out, int out_size, void* d_ws, size_t ws_size,
                              hipStream_t stream) {
    (void)in_sizes; (void)n_in; (void)out_size; (void)ws_size;
    const float* img = (const float*)d_in[0];
    const float* txt = (const float*)d_in[1];
    const float* cw  = (const float*)d_in[2];
    const int* labels = (const int*)d_in[3];
    float* out = (float*)d_out;
    char* wsb = (char*)d_ws;
    int* hist = (int*)(wsb + HIST_B);
    double* accum = (double*)(wsb + ACC_B);

    hipMemsetAsync(wsb + HIST_B, 0, 4096 + 16, stream);
    hist_kernel<<<16, 256, 0, stream>>>(labels, hist);
    prep_x_kernel<<<1024, 256, 0, stream>>>(cw, labels, hist, wsb);
    prep_y_kernel<<<dim3(1024, 2), 256, 0, stream>>>(img, txt, labels, wsb);
    fused_kernel<<<dim3(32, 32, 2), 512, 0, stream>>>(wsb, accum);
    merge_kernel<<<32, 256, 0, stream>>>(wsb, accum);
    finalize_kernel<<<1, 64, 0, stream>>>(accum, out);
}